// Round 4
// baseline (657.875 us; speedup 1.0000x reference)
//
#include <hip/hip_runtime.h>
#include <hip/hip_bf16.h>
#include <math.h>

// TransBlock on MI355X (gfx950). bf16 MFMA everywhere (threshold = 2% of absmax).
// R6: FIX R5's LN fold (it was per-d; LN affine is per-c = per GEMM row).
//     Correct fold: q = lw[c]*(xn@W^T)[c,o] + lb[c]*rowsum_W[o] + b[o] applied
//     in the mode-0 epilogue; cast_all computes rowsums; single shared xn.
//     Keep R5's T4 GEMM pipeline: 3-deep LDS, counted vmcnt(4), raw s_barrier.
// R4: BK=32, stats_fin folded into consumers. R3: attn XCD pinning.

typedef __bf16 bf16;
typedef __bf16 bf16x4 __attribute__((ext_vector_type(4)));
typedef __bf16 bf16x8 __attribute__((ext_vector_type(8)));
typedef float floatx4 __attribute__((ext_vector_type(4)));

#define MFMA16(a, b, c) __builtin_amdgcn_mfma_f32_16x16x32_bf16(a, b, c, 0, 0, 0)

__device__ __forceinline__ void gload16(const void* g, void* l) {
    __builtin_amdgcn_global_load_lds((__attribute__((address_space(1))) void*)g,
                                     (__attribute__((address_space(3))) void*)l,
                                     16, 0, 0);
}

// ------ cast fp32 -> bf16 for 5 weight matrices + QKV row-sums ---------------
// blocks 0..11263: cast one 1024-col row-chunk (plain, unscaled).
// blocks 11264..11311: rowsum_z[o] = sum_d W_z[o][d]  (48 blocks, 64 rows each)
__global__ __launch_bounds__(256)
void cast_all(const float* __restrict__ s0, bf16* __restrict__ d0_,
              const float* __restrict__ s1, bf16* __restrict__ d1_,
              const float* __restrict__ s2, bf16* __restrict__ d2_,
              const float* __restrict__ s3, bf16* __restrict__ d3_,
              const float* __restrict__ s4, bf16* __restrict__ d4_,
              float* __restrict__ rsumout)
{
    __shared__ float S[64][4];
    const int blk = blockIdx.x;
    const int tid = threadIdx.x;
    if (blk >= 11264) {
        const int j = blk - 11264;          // 0..47
        const int seg = j >> 4;             // 0:q 1:k 2:v
        const int obase = (j & 15) << 6;    // 0..960
        const float* W = seg == 0 ? s0 : (seg == 1 ? s1 : s2);
        float* outr = rsumout + (seg << 10);
        const int lane = tid & 63, wv_ = tid >> 6;
        for (int oi = 0; oi < 64; ++oi) {
            const float4 w4 = *(const float4*)(W + ((long)(obase + oi) << 10) + (tid << 2));
            float p = w4.x + w4.y + w4.z + w4.w;
#pragma unroll
            for (int off = 1; off < 64; off <<= 1) p += __shfl_xor(p, off, 64);
            if (lane == 0) S[oi][wv_] = p;
        }
        __syncthreads();
        if (tid < 64)
            outr[obase + tid] = S[tid][0] + S[tid][1] + S[tid][2] + S[tid][3];
        return;
    }
    const float* s; bf16* d; int base;
    if (blk < 1024)      { s = s0; d = d0_; base = blk; }
    else if (blk < 2048) { s = s1; d = d1_; base = blk - 1024; }
    else if (blk < 3072) { s = s2; d = d2_; base = blk - 2048; }
    else if (blk < 7168) { s = s3; d = d3_; base = blk - 3072; }
    else                 { s = s4; d = d4_; base = blk - 7168; }
    long i = ((long)base << 10) + (tid << 2);
    float4 v = *(const float4*)(s + i);
    bf16x4 o;
    o[0] = (bf16)v.x; o[1] = (bf16)v.y; o[2] = (bf16)v.z; o[3] = (bf16)v.w;
    *(bf16x4*)(d + i) = o;
}

// ------------- LN stats phase 1: partial sum/sumsq over 256-c chunk ----------
__global__ __launch_bounds__(256)
void stats_part(const float* __restrict__ xin, float* __restrict__ ps,
                float* __restrict__ pq)
{
    __shared__ float S1[4][64];
    __shared__ float S2[4][64];
    const int b = blockIdx.z, chunk = blockIdx.y;
    const int d0 = blockIdx.x << 6;
    const int tid = threadIdx.x;
    const int dl = tid & 63, cg = tid >> 6;
    const float* xp = xin + ((long)b << 20) + d0 + dl;
    const int cbase = (chunk << 8) + (cg << 6);
    float s = 0.f, sq = 0.f;
    for (int c = 0; c < 64; ++c) {
        float v = xp[(long)(cbase + c) << 10];
        s += v; sq += v * v;
    }
    S1[cg][dl] = s; S2[cg][dl] = sq;
    __syncthreads();
    if (tid < 64) {
        float ts = S1[0][tid] + S1[1][tid] + S1[2][tid] + S1[3][tid];
        float tq = S2[0][tid] + S2[1][tid] + S2[2][tid] + S2[3][tid];
        int idx = ((b * 4 + chunk) << 10) + d0 + tid;
        ps[idx] = ts; pq[idx] = tq;
    }
}

// ------------- normalize x1 once (pure (x-u)*rstd), cast bf16 ----------------
__global__ __launch_bounds__(256)
void ln_x1_kernel(const float* __restrict__ x1, const float* __restrict__ ps,
                  const float* __restrict__ pq, bf16* __restrict__ xn)
{
    const int bc = blockIdx.x;             // b*1024 + c
    const int b = bc >> 10;
    const int d = threadIdx.x << 2;
    const long i = ((long)bc << 10) + d;
    const float* pb = ps + (b << 12) + d;
    const float* qb = pq + (b << 12) + d;
    float s0 = 0.f, s1 = 0.f, s2 = 0.f, s3 = 0.f;
    float q0 = 0.f, q1 = 0.f, q2 = 0.f, q3 = 0.f;
#pragma unroll
    for (int c4 = 0; c4 < 4; ++c4) {
        float4 pv = *(const float4*)(pb + (c4 << 10));
        float4 qv = *(const float4*)(qb + (c4 << 10));
        s0 += pv.x; s1 += pv.y; s2 += pv.z; s3 += pv.w;
        q0 += qv.x; q1 += qv.y; q2 += qv.z; q3 += qv.w;
    }
    const float inv1024 = 1.f / 1024.f;
    float u0 = s0 * inv1024, u1 = s1 * inv1024, u2 = s2 * inv1024, u3 = s3 * inv1024;
    float r0 = rsqrtf(q0 * inv1024 - u0 * u0 + 1e-6f);
    float r1 = rsqrtf(q1 * inv1024 - u1 * u1 + 1e-6f);
    float r2 = rsqrtf(q2 * inv1024 - u2 * u2 + 1e-6f);
    float r3 = rsqrtf(q3 * inv1024 - u3 * u3 + 1e-6f);
    const float4 xv = *(const float4*)(x1 + i);
    bf16x4 o;
    o[0] = (bf16)((xv.x - u0) * r0);
    o[1] = (bf16)((xv.y - u1) * r1);
    o[2] = (bf16)((xv.z - u2) * r2);
    o[3] = (bf16)((xv.w - u3) * r3);
    *(bf16x4*)(xn + i) = o;
}

// --------- R6 BT GEMM: out[m,n] = sum_k A[m,k]*B[n,k], 128x128 tile ----------
// BK=32, 3-deep LDS pipeline (48 KB -> 3 blocks/CU). Counted vmcnt: per iter
// issue tile t+2 (4 loads/thread), ds_read tile t, then wait vmcnt(4) (tile
// t+1 resident; t+2's loads stay in flight ACROSS the raw s_barrier).
// mode 0: out bf16 = lnw[m]*acc + lnb[m]*rsum[n] + bias[n]   (LN-folded QKV)
// mode 1: out bf16 = gelu(acc + bias[n])                     (conv1 -> h1^T)
// mode 2: fp32: kz==0 -> Out = acc+bias[m]+R ;  kz>0 -> Part = acc (raw)
template<int MODE>
__global__ __launch_bounds__(256, 3)
void gemm_nt(const bf16* __restrict__ Ab, const bf16* __restrict__ Bb,
             void* __restrict__ Outb, float* __restrict__ Part,
             const float* __restrict__ bias0, const float* __restrict__ bias1,
             const float* __restrict__ bias2, const float* __restrict__ residb,
             const float* __restrict__ lnw0, const float* __restrict__ lnw1,
             const float* __restrict__ lnw2,
             const float* __restrict__ lnbq, const float* __restrict__ lnbk,
             const float* __restrict__ lnbv, const float* __restrict__ rsum,
             long sAz, long sBz, long sOz, long sRz, long sPz,
             int M, int N, int K, int Ksub, int zdiv)
{
    __shared__ __align__(16) bf16 As[3][128 * 32];
    __shared__ __align__(16) bf16 Bs[3][128 * 32];
    const int z = blockIdx.z;
    const int zb = z / zdiv, kz = z % zdiv;
    const bf16* A = Ab + (long)zb * sAz + (long)kz * Ksub;
    const bf16* B = Bb + (long)zb * sBz + (long)kz * Ksub;
    const float* bias = (zb == 0) ? bias0 : (zb == 1 ? bias1 : bias2);
    const int m0 = blockIdx.y << 7, n0 = blockIdx.x << 7;
    const int tid = threadIdx.x;
    const int wave = tid >> 6, lane = tid & 63;
    const int wm = (wave & 1) << 6, wn = (wave >> 1) << 6;
    const int lm = lane & 15, quad = lane >> 4;
    const long rA0 = (long)(tid >> 2) * K;
    const long rA1 = (long)((tid >> 2) + 64) * K;
    const int kc8 = (tid & 3) << 3;
    const bf16* Ag = A + (long)m0 * K + kc8;
    const bf16* Bg = B + (long)n0 * K + kc8;
    const int nt = Ksub >> 5;
    floatx4 acc[4][4] = {};

    auto STAGE = [&](int pf_, int kt_) {
        gload16(Ag + rA0 + kt_, &As[pf_][tid << 3]);
        gload16(Ag + rA1 + kt_, &As[pf_][(tid + 256) << 3]);
        gload16(Bg + rA0 + kt_, &Bs[pf_][tid << 3]);
        gload16(Bg + rA1 + kt_, &Bs[pf_][(tid + 256) << 3]);
    };

    STAGE(0, 0);
    STAGE(1, 32);
    asm volatile("s_waitcnt vmcnt(4)" ::: "memory");   // tile 0 resident
    __builtin_amdgcn_s_barrier();

    int cur = 0;
    for (int t = 0; t < nt; ++t) {
        if (t + 2 < nt) {
            int pf = cur - 1; if (pf < 0) pf += 3;     // (cur+2)%3
            STAGE(pf, (t + 2) << 5);
        }
        bf16x8 af[4], bfv[4];
#pragma unroll
        for (int i = 0; i < 4; ++i) {
            af[i]  = *(const bf16x8*)(&As[cur][((wm + i * 16 + lm) << 5) + (quad << 3)]);
            bfv[i] = *(const bf16x8*)(&Bs[cur][((wn + i * 16 + lm) << 5) + (quad << 3)]);
        }
        __builtin_amdgcn_s_setprio(1);
#pragma unroll
        for (int mi = 0; mi < 4; ++mi)
#pragma unroll
            for (int ni = 0; ni < 4; ++ni)
                acc[mi][ni] = MFMA16(af[mi], bfv[ni], acc[mi][ni]);
        __builtin_amdgcn_s_setprio(0);
        if (t + 2 < nt) asm volatile("s_waitcnt vmcnt(4)" ::: "memory");
        else            asm volatile("s_waitcnt vmcnt(0)" ::: "memory");
        __builtin_amdgcn_s_barrier();
        cur = (cur == 2) ? 0 : cur + 1;
    }

    const int quad4 = quad << 2;
    if (MODE == 2) {
        if (kz == 0) {
            float* Out = (float*)Outb + (long)zb * sOz;
            const float* R = residb + (long)zb * sRz;
#pragma unroll
            for (int mi = 0; mi < 4; ++mi)
#pragma unroll
                for (int ni = 0; ni < 4; ++ni)
#pragma unroll
                    for (int r = 0; r < 4; ++r) {
                        int row = m0 + wm + mi * 16 + quad4 + r;
                        int col = n0 + wn + ni * 16 + lm;
                        long idx = (long)row * N + col;
                        Out[idx] = acc[mi][ni][r] + bias[row] + R[idx];
                    }
        } else {
            float* Out = Part + (long)zb * sPz;
#pragma unroll
            for (int mi = 0; mi < 4; ++mi)
#pragma unroll
                for (int ni = 0; ni < 4; ++ni)
#pragma unroll
                    for (int r = 0; r < 4; ++r) {
                        int row = m0 + wm + mi * 16 + quad4 + r;
                        int col = n0 + wn + ni * 16 + lm;
                        Out[(long)row * N + col] = acc[mi][ni][r];
                    }
        }
    } else if (MODE == 0) {
        // LN-folded epilogue: lw[c]*acc + lb[c]*rowsum[o] + bias[o]
        bf16* Out = (bf16*)Outb + (long)zb * sOz;
        const float* lw = (zb == 0) ? lnw0 : (zb == 1 ? lnw1 : lnw2);
        const float* lb = (zb == 0) ? lnbq : (zb == 1 ? lnbk : lnbv);
        const float* rs = rsum + (zb << 10);
#pragma unroll
        for (int mi = 0; mi < 4; ++mi)
#pragma unroll
            for (int r = 0; r < 4; ++r) {
                const int row = m0 + wm + mi * 16 + quad4 + r;
                const int crow = row & 1023;   // M = 4*1024 (b,c); LN idx = c
                const float lwv = lw[crow], lbv = lb[crow];
#pragma unroll
                for (int ni = 0; ni < 4; ++ni) {
                    int col = n0 + wn + ni * 16 + lm;
                    float v = lwv * acc[mi][ni][r] + lbv * rs[col] + bias[col];
                    Out[(long)row * N + col] = (bf16)v;
                }
            }
    } else {
        bf16* Out = (bf16*)Outb + (long)zb * sOz;
#pragma unroll
        for (int mi = 0; mi < 4; ++mi)
#pragma unroll
            for (int ni = 0; ni < 4; ++ni)
#pragma unroll
                for (int r = 0; r < 4; ++r) {
                    int row = m0 + wm + mi * 16 + quad4 + r;
                    int col = n0 + wn + ni * 16 + lm;
                    float v = acc[mi][ni][r] + bias[col];
                    v = 0.5f * v * (1.0f + erff(v * 0.70710678118654752f));
                    Out[(long)row * N + col] = (bf16)v;
                }
    }
}

// ------------------ out0 += part (split-K reduce), float4 --------------------
__global__ __launch_bounds__(256)
void addpart(float* __restrict__ out, const float* __restrict__ part)
{
    long i = (((long)blockIdx.x << 8) + threadIdx.x) << 2;
    float4 o = *(const float4*)(out + i);
    float4 p = *(const float4*)(part + i);
    o.x += p.x; o.y += p.y; o.z += p.z; o.w += p.w;
    *(float4*)(out + i) = o;
}

// ---------------- V slab transpose: VT[p][e][k] = V[p][k][e] ------------------
__global__ __launch_bounds__(256)
void vtrans_kernel(const bf16* __restrict__ v, bf16* __restrict__ vt)
{
    __shared__ bf16 T[64][66];
    const int p = blockIdx.y;
    const int k0 = blockIdx.x << 6;
    const bf16* V = v + ((long)p << 16);
    bf16* Vt = vt + ((long)p << 16);
    const int tid = threadIdx.x;
    const int e = tid & 63, g = tid >> 6;
#pragma unroll
    for (int j = 0; j < 16; ++j) {
        int kk = (g << 4) + j;
        T[e][kk] = V[((long)(k0 + kk) << 6) + e];
    }
    __syncthreads();
#pragma unroll
    for (int j = 0; j < 16; ++j) {
        int er = (g << 4) + j;
        Vt[((long)er << 10) + k0 + e] = T[er][e];
    }
}

// ------- fused attention: S=QK^T/8, softmax-one, write weights, PV, +x1 -------
// 1D grid, XCD-aware decode: p-octet pinned per XCD so its L2 owns 8 KV slabs.
__global__ __launch_bounds__(256)
void attn_kernel(const bf16* __restrict__ q, const bf16* __restrict__ k,
                 const bf16* __restrict__ vt, const float* __restrict__ x1,
                 float* __restrict__ attw, float* __restrict__ x)
{
    __shared__ __align__(16) bf16 Wl[16][1032];   // weights (bf16): PV A-op + attw source
    __shared__ float red[16][4];
    const int bid = blockIdx.x;
    const int p = ((bid & 7) << 3) | ((bid >> 3) & 7);   // (b,h) 0..63
    const int s = bid >> 6;                              // q-stripe 0..63
    const int b = p >> 4, h = p & 15;
    const bf16* Qp = q + ((long)b << 20) + ((long)h << 16);
    const bf16* Kp = k + ((long)b << 20) + ((long)h << 16);
    const bf16* Vt = vt + ((long)p << 16);
    const int tid = threadIdx.x, w = tid >> 6, lane = tid & 63;
    const int lm = lane & 15, quad = lane >> 4;
    const int r0 = s << 4, kc0 = w << 8;

    floatx4 acc[16];
#pragma unroll
    for (int t = 0; t < 16; ++t) acc[t] = (floatx4){0.f, 0.f, 0.f, 0.f};

#pragma unroll
    for (int e0 = 0; e0 < 64; e0 += 32) {
        bf16x8 aq = *(const bf16x8*)(Qp + ((long)(r0 + lm) << 6) + e0 + quad * 8);
#pragma unroll
        for (int t = 0; t < 16; ++t) {
            bf16x8 bk = *(const bf16x8*)(Kp + ((long)(kc0 + t * 16 + lm) << 6) + e0 + quad * 8);
            acc[t] = MFMA16(aq, bk, acc[t]);
        }
    }
#pragma unroll
    for (int t = 0; t < 16; ++t)
#pragma unroll
        for (int r = 0; r < 4; ++r) acc[t][r] *= 0.125f;   // 1/sqrt(64)

    float mloc[4];
#pragma unroll
    for (int r = 0; r < 4; ++r) {
        float mm = acc[0][r];
#pragma unroll
        for (int t = 1; t < 16; ++t) mm = fmaxf(mm, acc[t][r]);
        mloc[r] = mm;
    }
#pragma unroll
    for (int off = 1; off < 16; off <<= 1)
#pragma unroll
        for (int r = 0; r < 4; ++r) mloc[r] = fmaxf(mloc[r], __shfl_xor(mloc[r], off, 64));
    if (lm == 0)
#pragma unroll
        for (int r = 0; r < 4; ++r) red[quad * 4 + r][w] = mloc[r];
    __syncthreads();
    float mfin[4];
#pragma unroll
    for (int r = 0; r < 4; ++r) {
        int row = quad * 4 + r;
        mfin[r] = fmaxf(fmaxf(red[row][0], red[row][1]), fmaxf(red[row][2], red[row][3]));
    }
    float sloc[4] = {0.f, 0.f, 0.f, 0.f};
#pragma unroll
    for (int t = 0; t < 16; ++t)
#pragma unroll
        for (int r = 0; r < 4; ++r) {
            float e = __expf(acc[t][r] - mfin[r]);
            acc[t][r] = e;
            sloc[r] += e;
        }
#pragma unroll
    for (int off = 1; off < 16; off <<= 1)
#pragma unroll
        for (int r = 0; r < 4; ++r) sloc[r] += __shfl_xor(sloc[r], off, 64);
    __syncthreads();
    if (lm == 0)
#pragma unroll
        for (int r = 0; r < 4; ++r) red[quad * 4 + r][w] = sloc[r];
    __syncthreads();
    float inv[4];
#pragma unroll
    for (int r = 0; r < 4; ++r) {
        int row = quad * 4 + r;
        inv[r] = 1.f / (1.f + red[row][0] + red[row][1] + red[row][2] + red[row][3]);
    }
    // normalized weights -> LDS (bf16) only; global write comes later, coalesced
#pragma unroll
    for (int r = 0; r < 4; ++r) {
        int row = quad * 4 + r;
        float iv = inv[r];
#pragma unroll
        for (int t = 0; t < 16; ++t)
            Wl[row][kc0 + t * 16 + lm] = (bf16)(acc[t][r] * iv);
    }
    __syncthreads();

    // PV: O(16x64) = W(16x1024) @ V(1024x64), wave w covers k in [kc0,kc0+256)
    floatx4 opv[4];
#pragma unroll
    for (int ni = 0; ni < 4; ++ni) opv[ni] = (floatx4){0.f, 0.f, 0.f, 0.f};
#pragma unroll
    for (int i = 0; i < 8; ++i) {
        const int kk = kc0 + i * 32;
        bf16x8 a0 = *(const bf16x8*)&Wl[lm][kk + quad * 8];
#pragma unroll
        for (int ni = 0; ni < 4; ++ni) {
            bf16x8 bv = *(const bf16x8*)(Vt + ((long)(ni * 16 + lm) << 10) + kk + quad * 8);
            opv[ni] = MFMA16(a0, bv, opv[ni]);
        }
    }
    // coalesced attw write from Wl: 16 rows x 1024 cols fp32, float4/lane/iter
    {
        float* attp = attw + ((long)p << 20) + ((long)r0 << 10);
#pragma unroll
        for (int i = 0; i < 16; ++i) {
            int v4 = (i << 8) + tid;
            int row = v4 >> 8, col = (v4 & 255) << 2;
            bf16x4 wv = *(const bf16x4*)&Wl[row][col];
            floatx4 o = {(float)wv[0], (float)wv[1], (float)wv[2], (float)wv[3]};
            __builtin_nontemporal_store(o, (floatx4*)(attp + ((long)row << 10) + col));
        }
    }
    __syncthreads();
    float* Ored = (float*)&Wl[0][0];   // [4][16][64], aliases Wl (dead now)
#pragma unroll
    for (int ni = 0; ni < 4; ++ni)
#pragma unroll
        for (int r = 0; r < 4; ++r)
            Ored[(w * 16 + quad * 4 + r) * 64 + ni * 16 + lm] = opv[ni][r];
    __syncthreads();
    const float* x1p = x1 + ((long)b << 20) + ((long)r0 << 10) + (h << 6);
    float* xp = x + ((long)b << 20) + ((long)r0 << 10) + (h << 6);
#pragma unroll
    for (int j = 0; j < 4; ++j) {
        int el = tid + (j << 8);
        int row = el >> 6, cc = el & 63;
        float o = Ored[row * 64 + cc] + Ored[(16 + row) * 64 + cc]
                + Ored[(32 + row) * 64 + cc] + Ored[(48 + row) * 64 + cc];
        xp[((long)row << 10) + cc] = x1p[((long)row << 10) + cc] + o;
    }
}

// --------- FFN LN + transpose: xlT[b][l][c] = ffw[c]*(x-u)*rstd + ffb[c] ------
__global__ __launch_bounds__(256)
void ln_ffn_t_kernel(const float* __restrict__ x, const float* __restrict__ ps,
                     const float* __restrict__ pq, const float* __restrict__ fw,
                     const float* __restrict__ fb, bf16* __restrict__ xlT)
{
    __shared__ bf16 T[64][66];
    const int b = blockIdx.z;
    const int l0 = blockIdx.x << 6, c0 = blockIdx.y << 6;
    const int tid = threadIdx.x;
    const int ll = tid & 63, g = tid >> 6;
    float s = 0.f, q = 0.f;
#pragma unroll
    for (int c4 = 0; c4 < 4; ++c4) {
        s += ps[(b << 12) + (c4 << 10) + l0 + ll];
        q += pq[(b << 12) + (c4 << 10) + l0 + ll];
    }
    const float uu = s * (1.f / 1024.f);
    const float rr = rsqrtf(q * (1.f / 1024.f) - uu * uu + 1e-6f);
#pragma unroll
    for (int j = 0; j < 16; ++j) {
        int cc = (g << 4) + j;
        float v = x[((long)b << 20) + ((long)(c0 + cc) << 10) + l0 + ll];
        T[ll][cc] = (bf16)(fw[c0 + cc] * (v - uu) * rr + fb[c0 + cc]);
    }
    __syncthreads();
#pragma unroll
    for (int j = 0; j < 16; ++j) {
        int lr = (g << 4) + j;
        xlT[((long)b << 20) + ((long)(l0 + lr) << 10) + c0 + ll] = T[lr][ll];
    }
}

extern "C" void kernel_launch(void* const* d_in, const int* in_sizes, int n_in,
                              void* d_out, int out_size, void* d_ws, size_t ws_size,
                              hipStream_t stream)
{
    const float* x1      = (const float*)d_in[0];
    const float* lnq_w   = (const float*)d_in[1];
    const float* lnq_b   = (const float*)d_in[2];
    const float* lnk_w   = (const float*)d_in[3];
    const float* lnk_b   = (const float*)d_in[4];
    const float* lnv_w   = (const float*)d_in[5];
    const float* lnv_b   = (const float*)d_in[6];
    const float* wq      = (const float*)d_in[7];
    const float* bq      = (const float*)d_in[8];
    const float* wk      = (const float*)d_in[9];
    const float* bk      = (const float*)d_in[10];
    const float* wv      = (const float*)d_in[11];
    const float* bv      = (const float*)d_in[12];
    const float* ffnln_w = (const float*)d_in[13];
    const float* ffnln_b = (const float*)d_in[14];
    const float* conv1_w = (const float*)d_in[15];
    const float* conv1_b = (const float*)d_in[16];
    const float* conv2_w = (const float*)d_in[17];
    const float* conv2_b = (const float*)d_in[18];
    (void)in_sizes; (void)n_in; (void)out_size; (void)ws_size;

    char* ws = (char*)d_ws;
    // header: rsum_qkv (12KB) @0 + ps/pq partials (64KB each) -> 256KB
    const size_t OFF_VT   = 262144;                   //  8 MB VT        [h1T overlay]
    const size_t OFF_QKV  = OFF_VT   + 8388608;       // 24 MB q,k,v bf16 [h1T overlay]
    const size_t OFF_WQKV = OFF_QKV  + 25165824;      //  8 MB wq/wk/wv bf16 [xlT / part overlay]
    const size_t OFF_W1   = OFF_WQKV + 8388608;       //  8 MB conv1_w bf16  [part overlay]
    const size_t OFF_X    = OFF_W1   + 8388608;       // 16 MB x = x1 + attn_out (fp32)
    const size_t OFF_W2   = OFF_X    + 16777216;      //  8 MB conv2_w bf16
    float* rsum  = (float*)(ws + 0);
    float* ps    = (float*)(ws + 65536);
    float* pq    = (float*)(ws + 131072);
    bf16*  vt    = (bf16*)(ws + OFF_VT);
    bf16*  qkv   = (bf16*)(ws + OFF_QKV);
    bf16*  wqkvb = (bf16*)(ws + OFF_WQKV);
    bf16*  w1b   = (bf16*)(ws + OFF_W1);
    float* x     = (float*)(ws + OFF_X);
    bf16*  w2b   = (bf16*)(ws + OFF_W2);
    bf16*  h1T   = (bf16*)(ws + OFF_VT);              // 32 MB, overlays vt+qkv (dead post-attn)
    bf16*  xlT   = (bf16*)(ws + OFF_WQKV);            //  8 MB, overlays wqkvb (dead post-QKV)
    float* part  = (float*)(ws + OFF_WQKV);           // 16 MB, overlays wqkvb+w1b (dead at conv2)

    float* out0 = (float*)d_out;
    float* attw = (float*)((char*)d_out + 16777216);  // 4*16*1024*1024 fp32
    bf16*  xn   = (bf16*)attw;                        //  8 MB scratch, dead before attn writes

    // 1. weight casts + QKV row-sums (for the LN-bias fold)
    cast_all<<<11312, 256, 0, stream>>>(wq, wqkvb, wk, wqkvb + (1 << 20),
                                        wv, wqkvb + (2 << 20), conv1_w, w1b, conv2_w, w2b,
                                        rsum);
    // 2. LN stats of x1 (partials only; finalize fused into consumers)
    stats_part<<<dim3(16, 4, 4), 256, 0, stream>>>(x1, ps, pq);
    // 3. single normalized input xn (bf16)
    ln_x1_kernel<<<4096, 256, 0, stream>>>(x1, ps, pq, xn);
    // 4. QKV projections: shared A (sAz=0), LN affine folded into epilogue
    gemm_nt<0><<<dim3(8, 32, 3), 256, 0, stream>>>(xn, wqkvb, qkv, nullptr,
                                                   bq, bk, bv, nullptr,
                                                   lnq_w, lnk_w, lnv_w,
                                                   lnq_b, lnk_b, lnv_b, rsum,
                                                   0, 1L << 20, 1L << 22, 0, 0,
                                                   4096, 1024, 1024, 1024, 1);
    // 5. V^T slabs for PV B-operand
    vtrans_kernel<<<dim3(16, 64), 256, 0, stream>>>(qkv + (2L << 22), vt);
    // 6. fused attention (attn weights fp32 + x = x1 + o), XCD-aware 1D grid
    attn_kernel<<<4096, 256, 0, stream>>>(qkv, qkv + (1L << 22), vt, x1, attw, x);
    // 7. FFN LN stats of x (partials only)
    stats_part<<<dim3(16, 4, 4), 256, 0, stream>>>(x, ps, pq);
    // 8. FFN LN + transpose -> xlT (bf16)
    ln_ffn_t_kernel<<<dim3(16, 16, 4), 256, 0, stream>>>(x, ps, pq, ffnln_w, ffnln_b, xlT);
    // 9. conv1: h1T[b] = gelu(xlT[b] @ conv1_w^T + b1)   (M=1024,N=4096,K=1024)
    gemm_nt<1><<<dim3(32, 8, 4), 256, 0, stream>>>(xlT, w1b, h1T, nullptr,
                                                   conv1_b, conv1_b, conv1_b, nullptr,
                                                   nullptr, nullptr, nullptr,
                                                   nullptr, nullptr, nullptr, nullptr,
                                                   1L << 20, 0, 1L << 22, 0, 0,
                                                   1024, 4096, 1024, 1024, 1);
    // 10. conv2 split-K: out0[b] = conv2_w @ h1T[b]^T + b2 + x[b]  (K=4096 -> 2x2048)
    gemm_nt<2><<<dim3(8, 8, 8), 256, 0, stream>>>(w2b, h1T, out0, part,
                                                  conv2_b, conv2_b, conv2_b, x,
                                                  nullptr, nullptr, nullptr,
                                                  nullptr, nullptr, nullptr, nullptr,
                                                  0, 1L << 22, 1L << 20, 1L << 20,
                                                  1L << 20, 1024, 1024, 4096, 2048, 2);
    // 11. out0 += part
    addpart<<<4096, 256, 0, stream>>>(out0, part);
}

// Round 5
// 637.252 us; speedup vs baseline: 1.0324x; 1.0324x over previous
//
#include <hip/hip_runtime.h>
#include <hip/hip_bf16.h>
#include <math.h>

// TransBlock on MI355X (gfx950). bf16 MFMA everywhere (threshold = 2% of absmax).
// R7: REVERT R6's counted-vmcnt pipeline (regressed 622->658; T4 requires the
//     8-phase role-split per the regime gate - on 2-phase loops asm waits just
//     defeat compiler scheduling, m141). Back to R4's K-loop: dbuf-2, issue-
//     early prefetch, __syncthreads, 3 blocks/CU. Keep R6's (correct) LN fold.
//     New: conv1 gelu via sigmoid-form tanh approx (1 exp vs ~30-op erff);
//     stats_part(x1) folded into cast_all (-1 dispatch).
// R4: BK=32 dbuf. R3: attn XCD pinning.

typedef __bf16 bf16;
typedef __bf16 bf16x4 __attribute__((ext_vector_type(4)));
typedef __bf16 bf16x8 __attribute__((ext_vector_type(8)));
typedef float floatx4 __attribute__((ext_vector_type(4)));

#define MFMA16(a, b, c) __builtin_amdgcn_mfma_f32_16x16x32_bf16(a, b, c, 0, 0, 0)

__device__ __forceinline__ void gload16(const void* g, void* l) {
    __builtin_amdgcn_global_load_lds((__attribute__((address_space(1))) void*)g,
                                     (__attribute__((address_space(3))) void*)l,
                                     16, 0, 0);
}

// ------ cast fp32 -> bf16 for 5 weight matrices + QKV row-sums + LN stats ----
// blocks 0..11263:      cast one 1024-col row-chunk (plain, unscaled).
// blocks 11264..11311:  rowsum_z[o] = sum_d W_z[o][d] (48 blocks)
// blocks 11312..11567:  LN stats partials of x1 (256 blocks = old stats_part)
__global__ __launch_bounds__(256)
void cast_all(const float* __restrict__ s0, bf16* __restrict__ d0_,
              const float* __restrict__ s1, bf16* __restrict__ d1_,
              const float* __restrict__ s2, bf16* __restrict__ d2_,
              const float* __restrict__ s3, bf16* __restrict__ d3_,
              const float* __restrict__ s4, bf16* __restrict__ d4_,
              float* __restrict__ rsumout,
              const float* __restrict__ x1, float* __restrict__ ps,
              float* __restrict__ pq)
{
    __shared__ float S[64][4];
    __shared__ float S1[4][64];
    __shared__ float S2[4][64];
    const int blk = blockIdx.x;
    const int tid = threadIdx.x;
    if (blk >= 11312) {
        // LN stats partials of x1
        const int j = blk - 11312;          // 0..255
        const int d0 = (j & 15) << 6;
        const int chunk = (j >> 4) & 3;
        const int b = j >> 6;
        const int dl = tid & 63, cg = tid >> 6;
        const float* xp = x1 + ((long)b << 20) + d0 + dl;
        const int cbase = (chunk << 8) + (cg << 6);
        float s = 0.f, sq = 0.f;
        for (int c = 0; c < 64; ++c) {
            float v = xp[(long)(cbase + c) << 10];
            s += v; sq += v * v;
        }
        S1[cg][dl] = s; S2[cg][dl] = sq;
        __syncthreads();
        if (tid < 64) {
            float ts = S1[0][tid] + S1[1][tid] + S1[2][tid] + S1[3][tid];
            float tq = S2[0][tid] + S2[1][tid] + S2[2][tid] + S2[3][tid];
            int idx = ((b * 4 + chunk) << 10) + d0 + tid;
            ps[idx] = ts; pq[idx] = tq;
        }
        return;
    }
    if (blk >= 11264) {
        const int j = blk - 11264;          // 0..47
        const int seg = j >> 4;             // 0:q 1:k 2:v
        const int obase = (j & 15) << 6;    // 0..960
        const float* W = seg == 0 ? s0 : (seg == 1 ? s1 : s2);
        float* outr = rsumout + (seg << 10);
        const int lane = tid & 63, wv_ = tid >> 6;
        for (int oi = 0; oi < 64; ++oi) {
            const float4 w4 = *(const float4*)(W + ((long)(obase + oi) << 10) + (tid << 2));
            float p = w4.x + w4.y + w4.z + w4.w;
#pragma unroll
            for (int off = 1; off < 64; off <<= 1) p += __shfl_xor(p, off, 64);
            if (lane == 0) S[oi][wv_] = p;
        }
        __syncthreads();
        if (tid < 64)
            outr[obase + tid] = S[tid][0] + S[tid][1] + S[tid][2] + S[tid][3];
        return;
    }
    const float* s; bf16* d; int base;
    if (blk < 1024)      { s = s0; d = d0_; base = blk; }
    else if (blk < 2048) { s = s1; d = d1_; base = blk - 1024; }
    else if (blk < 3072) { s = s2; d = d2_; base = blk - 2048; }
    else if (blk < 7168) { s = s3; d = d3_; base = blk - 3072; }
    else                 { s = s4; d = d4_; base = blk - 7168; }
    long i = ((long)base << 10) + (tid << 2);
    float4 v = *(const float4*)(s + i);
    bf16x4 o;
    o[0] = (bf16)v.x; o[1] = (bf16)v.y; o[2] = (bf16)v.z; o[3] = (bf16)v.w;
    *(bf16x4*)(d + i) = o;
}

// ------------- LN stats phase 1: partial sum/sumsq over 256-c chunk ----------
__global__ __launch_bounds__(256)
void stats_part(const float* __restrict__ xin, float* __restrict__ ps,
                float* __restrict__ pq)
{
    __shared__ float S1[4][64];
    __shared__ float S2[4][64];
    const int b = blockIdx.z, chunk = blockIdx.y;
    const int d0 = blockIdx.x << 6;
    const int tid = threadIdx.x;
    const int dl = tid & 63, cg = tid >> 6;
    const float* xp = xin + ((long)b << 20) + d0 + dl;
    const int cbase = (chunk << 8) + (cg << 6);
    float s = 0.f, sq = 0.f;
    for (int c = 0; c < 64; ++c) {
        float v = xp[(long)(cbase + c) << 10];
        s += v; sq += v * v;
    }
    S1[cg][dl] = s; S2[cg][dl] = sq;
    __syncthreads();
    if (tid < 64) {
        float ts = S1[0][tid] + S1[1][tid] + S1[2][tid] + S1[3][tid];
        float tq = S2[0][tid] + S2[1][tid] + S2[2][tid] + S2[3][tid];
        int idx = ((b * 4 + chunk) << 10) + d0 + tid;
        ps[idx] = ts; pq[idx] = tq;
    }
}

// ------------- normalize x1 once (pure (x-u)*rstd), cast bf16 ----------------
__global__ __launch_bounds__(256)
void ln_x1_kernel(const float* __restrict__ x1, const float* __restrict__ ps,
                  const float* __restrict__ pq, bf16* __restrict__ xn)
{
    const int bc = blockIdx.x;             // b*1024 + c
    const int b = bc >> 10;
    const int d = threadIdx.x << 2;
    const long i = ((long)bc << 10) + d;
    const float* pb = ps + (b << 12) + d;
    const float* qb = pq + (b << 12) + d;
    float s0 = 0.f, s1 = 0.f, s2 = 0.f, s3 = 0.f;
    float q0 = 0.f, q1 = 0.f, q2 = 0.f, q3 = 0.f;
#pragma unroll
    for (int c4 = 0; c4 < 4; ++c4) {
        float4 pv = *(const float4*)(pb + (c4 << 10));
        float4 qv = *(const float4*)(qb + (c4 << 10));
        s0 += pv.x; s1 += pv.y; s2 += pv.z; s3 += pv.w;
        q0 += qv.x; q1 += qv.y; q2 += qv.z; q3 += qv.w;
    }
    const float inv1024 = 1.f / 1024.f;
    float u0 = s0 * inv1024, u1 = s1 * inv1024, u2 = s2 * inv1024, u3 = s3 * inv1024;
    float r0 = rsqrtf(q0 * inv1024 - u0 * u0 + 1e-6f);
    float r1 = rsqrtf(q1 * inv1024 - u1 * u1 + 1e-6f);
    float r2 = rsqrtf(q2 * inv1024 - u2 * u2 + 1e-6f);
    float r3 = rsqrtf(q3 * inv1024 - u3 * u3 + 1e-6f);
    const float4 xv = *(const float4*)(x1 + i);
    bf16x4 o;
    o[0] = (bf16)((xv.x - u0) * r0);
    o[1] = (bf16)((xv.y - u1) * r1);
    o[2] = (bf16)((xv.z - u2) * r2);
    o[3] = (bf16)((xv.w - u3) * r3);
    *(bf16x4*)(xn + i) = o;
}

// --------- R7 BT GEMM: out[m,n] = sum_k A[m,k]*B[n,k], 128x128 tile ----------
// R4 K-loop restored: BK=32, double-buffered LDS (32 KB -> 3 blocks/CU),
// issue-early global_load_lds prefetch of t+1 before t's ds_reads, setprio
// around MFMA cluster, ONE __syncthreads per 32-K tile.
// mode 0: out bf16 = lnw[m]*acc + lnb[m]*rsum[n] + bias[n]   (LN-folded QKV)
// mode 1: out bf16 = gelu_fast(acc + bias[n])                (conv1 -> h1^T)
// mode 2: fp32: kz==0 -> Out = acc+bias[m]+R ;  kz>0 -> Part = acc (raw)
template<int MODE>
__global__ __launch_bounds__(256, 3)
void gemm_nt(const bf16* __restrict__ Ab, const bf16* __restrict__ Bb,
             void* __restrict__ Outb, float* __restrict__ Part,
             const float* __restrict__ bias0, const float* __restrict__ bias1,
             const float* __restrict__ bias2, const float* __restrict__ residb,
             const float* __restrict__ lnw0, const float* __restrict__ lnw1,
             const float* __restrict__ lnw2,
             const float* __restrict__ lnbq, const float* __restrict__ lnbk,
             const float* __restrict__ lnbv, const float* __restrict__ rsum,
             long sAz, long sBz, long sOz, long sRz, long sPz,
             int M, int N, int K, int Ksub, int zdiv)
{
    __shared__ __align__(16) bf16 As[2][128 * 32];
    __shared__ __align__(16) bf16 Bs[2][128 * 32];
    const int z = blockIdx.z;
    const int zb = z / zdiv, kz = z % zdiv;
    const bf16* A = Ab + (long)zb * sAz + (long)kz * Ksub;
    const bf16* B = Bb + (long)zb * sBz + (long)kz * Ksub;
    const float* bias = (zb == 0) ? bias0 : (zb == 1 ? bias1 : bias2);
    const int m0 = blockIdx.y << 7, n0 = blockIdx.x << 7;
    const int tid = threadIdx.x;
    const int wave = tid >> 6, lane = tid & 63;
    const int wm = (wave & 1) << 6, wn = (wave >> 1) << 6;
    const int lm = lane & 15, quad = lane >> 4;
    const bf16* Ag = A + (long)m0 * K;
    const bf16* Bg = B + (long)n0 * K;
    const int nt = Ksub >> 5;
    floatx4 acc[4][4] = {};

    // prologue: stage K-tile 0 into buf 0
#pragma unroll
    for (int r_ = 0; r_ < 2; ++r_) {
        int s_ = (r_ << 8) + tid;          // 0..511
        int lrow = s_ >> 2;                // 0..127
        long go = (long)lrow * K + ((s_ & 3) << 3);
        gload16(Ag + go, &As[0][s_ << 3]);
        gload16(Bg + go, &Bs[0][s_ << 3]);
    }
    __syncthreads();   // vmcnt(0) drain -> tile 0 resident

    for (int t = 0; t < nt; ++t) {
        const int cur = t & 1;
        // issue-early: prefetch K-tile t+1 into the idle buffer FIRST
        if (t + 1 < nt) {
            const int kofs = (t + 1) << 5;
#pragma unroll
            for (int r_ = 0; r_ < 2; ++r_) {
                int s_ = (r_ << 8) + tid;
                int lrow = s_ >> 2;
                long go = (long)lrow * K + kofs + ((s_ & 3) << 3);
                gload16(Ag + go, &As[cur ^ 1][s_ << 3]);
                gload16(Bg + go, &Bs[cur ^ 1][s_ << 3]);
            }
        }
        bf16x8 af[4], bfv[4];
#pragma unroll
        for (int i = 0; i < 4; ++i) {
            af[i]  = *(const bf16x8*)(&As[cur][((wm + i * 16 + lm) << 5) + (quad << 3)]);
            bfv[i] = *(const bf16x8*)(&Bs[cur][((wn + i * 16 + lm) << 5) + (quad << 3)]);
        }
        __builtin_amdgcn_s_setprio(1);
#pragma unroll
        for (int mi = 0; mi < 4; ++mi)
#pragma unroll
            for (int ni = 0; ni < 4; ++ni)
                acc[mi][ni] = MFMA16(af[mi], bfv[ni], acc[mi][ni]);
        __builtin_amdgcn_s_setprio(0);
        __syncthreads();   // one barrier per 32-K tile
    }

    const int quad4 = quad << 2;
    if (MODE == 2) {
        if (kz == 0) {
            float* Out = (float*)Outb + (long)zb * sOz;
            const float* R = residb + (long)zb * sRz;
#pragma unroll
            for (int mi = 0; mi < 4; ++mi)
#pragma unroll
                for (int ni = 0; ni < 4; ++ni)
#pragma unroll
                    for (int r = 0; r < 4; ++r) {
                        int row = m0 + wm + mi * 16 + quad4 + r;
                        int col = n0 + wn + ni * 16 + lm;
                        long idx = (long)row * N + col;
                        Out[idx] = acc[mi][ni][r] + bias[row] + R[idx];
                    }
        } else {
            float* Out = Part + (long)zb * sPz;
#pragma unroll
            for (int mi = 0; mi < 4; ++mi)
#pragma unroll
                for (int ni = 0; ni < 4; ++ni)
#pragma unroll
                    for (int r = 0; r < 4; ++r) {
                        int row = m0 + wm + mi * 16 + quad4 + r;
                        int col = n0 + wn + ni * 16 + lm;
                        Out[(long)row * N + col] = acc[mi][ni][r];
                    }
        }
    } else if (MODE == 0) {
        // LN-folded epilogue: lw[c]*acc + lb[c]*rowsum[o] + bias[o]
        bf16* Out = (bf16*)Outb + (long)zb * sOz;
        const float* lw = (zb == 0) ? lnw0 : (zb == 1 ? lnw1 : lnw2);
        const float* lb = (zb == 0) ? lnbq : (zb == 1 ? lnbk : lnbv);
        const float* rs = rsum + (zb << 10);
#pragma unroll
        for (int mi = 0; mi < 4; ++mi)
#pragma unroll
            for (int r = 0; r < 4; ++r) {
                const int row = m0 + wm + mi * 16 + quad4 + r;
                const int crow = row & 1023;   // M = 4*1024 (b,c); LN idx = c
                const float lwv = lw[crow], lbv = lb[crow];
#pragma unroll
                for (int ni = 0; ni < 4; ++ni) {
                    int col = n0 + wn + ni * 16 + lm;
                    float v = lwv * acc[mi][ni][r] + lbv * rs[col] + bias[col];
                    Out[(long)row * N + col] = (bf16)v;
                }
            }
    } else {
        bf16* Out = (bf16*)Outb + (long)zb * sOz;
#pragma unroll
        for (int mi = 0; mi < 4; ++mi)
#pragma unroll
            for (int ni = 0; ni < 4; ++ni)
#pragma unroll
                for (int r = 0; r < 4; ++r) {
                    int row = m0 + wm + mi * 16 + quad4 + r;
                    int col = n0 + wn + ni * 16 + lm;
                    float v = acc[mi][ni][r] + bias[col];
                    // gelu via sigmoid-form tanh approx: v * sigmoid(2u),
                    // 2u = 1.5957691216 v + 0.0713548162 v^3 (err ~1e-3 << thr)
                    float g = 1.5957691216f * v + 0.0713548162f * v * v * v;
                    v = v / (1.0f + __expf(-g));
                    Out[(long)row * N + col] = (bf16)v;
                }
    }
}

// ------------------ out0 += part (split-K reduce), float4 --------------------
__global__ __launch_bounds__(256)
void addpart(float* __restrict__ out, const float* __restrict__ part)
{
    long i = (((long)blockIdx.x << 8) + threadIdx.x) << 2;
    float4 o = *(const float4*)(out + i);
    float4 p = *(const float4*)(part + i);
    o.x += p.x; o.y += p.y; o.z += p.z; o.w += p.w;
    *(float4*)(out + i) = o;
}

// ---------------- V slab transpose: VT[p][e][k] = V[p][k][e] ------------------
__global__ __launch_bounds__(256)
void vtrans_kernel(const bf16* __restrict__ v, bf16* __restrict__ vt)
{
    __shared__ bf16 T[64][66];
    const int p = blockIdx.y;
    const int k0 = blockIdx.x << 6;
    const bf16* V = v + ((long)p << 16);
    bf16* Vt = vt + ((long)p << 16);
    const int tid = threadIdx.x;
    const int e = tid & 63, g = tid >> 6;
#pragma unroll
    for (int j = 0; j < 16; ++j) {
        int kk = (g << 4) + j;
        T[e][kk] = V[((long)(k0 + kk) << 6) + e];
    }
    __syncthreads();
#pragma unroll
    for (int j = 0; j < 16; ++j) {
        int er = (g << 4) + j;
        Vt[((long)er << 10) + k0 + e] = T[er][e];
    }
}

// ------- fused attention: S=QK^T/8, softmax-one, write weights, PV, +x1 -------
// 1D grid, XCD-aware decode: p-octet pinned per XCD so its L2 owns 8 KV slabs.
__global__ __launch_bounds__(256)
void attn_kernel(const bf16* __restrict__ q, const bf16* __restrict__ k,
                 const bf16* __restrict__ vt, const float* __restrict__ x1,
                 float* __restrict__ attw, float* __restrict__ x)
{
    __shared__ __align__(16) bf16 Wl[16][1032];   // weights (bf16): PV A-op + attw source
    __shared__ float red[16][4];
    const int bid = blockIdx.x;
    const int p = ((bid & 7) << 3) | ((bid >> 3) & 7);   // (b,h) 0..63
    const int s = bid >> 6;                              // q-stripe 0..63
    const int b = p >> 4, h = p & 15;
    const bf16* Qp = q + ((long)b << 20) + ((long)h << 16);
    const bf16* Kp = k + ((long)b << 20) + ((long)h << 16);
    const bf16* Vt = vt + ((long)p << 16);
    const int tid = threadIdx.x, w = tid >> 6, lane = tid & 63;
    const int lm = lane & 15, quad = lane >> 4;
    const int r0 = s << 4, kc0 = w << 8;

    floatx4 acc[16];
#pragma unroll
    for (int t = 0; t < 16; ++t) acc[t] = (floatx4){0.f, 0.f, 0.f, 0.f};

#pragma unroll
    for (int e0 = 0; e0 < 64; e0 += 32) {
        bf16x8 aq = *(const bf16x8*)(Qp + ((long)(r0 + lm) << 6) + e0 + quad * 8);
#pragma unroll
        for (int t = 0; t < 16; ++t) {
            bf16x8 bk = *(const bf16x8*)(Kp + ((long)(kc0 + t * 16 + lm) << 6) + e0 + quad * 8);
            acc[t] = MFMA16(aq, bk, acc[t]);
        }
    }
#pragma unroll
    for (int t = 0; t < 16; ++t)
#pragma unroll
        for (int r = 0; r < 4; ++r) acc[t][r] *= 0.125f;   // 1/sqrt(64)

    float mloc[4];
#pragma unroll
    for (int r = 0; r < 4; ++r) {
        float mm = acc[0][r];
#pragma unroll
        for (int t = 1; t < 16; ++t) mm = fmaxf(mm, acc[t][r]);
        mloc[r] = mm;
    }
#pragma unroll
    for (int off = 1; off < 16; off <<= 1)
#pragma unroll
        for (int r = 0; r < 4; ++r) mloc[r] = fmaxf(mloc[r], __shfl_xor(mloc[r], off, 64));
    if (lm == 0)
#pragma unroll
        for (int r = 0; r < 4; ++r) red[quad * 4 + r][w] = mloc[r];
    __syncthreads();
    float mfin[4];
#pragma unroll
    for (int r = 0; r < 4; ++r) {
        int row = quad * 4 + r;
        mfin[r] = fmaxf(fmaxf(red[row][0], red[row][1]), fmaxf(red[row][2], red[row][3]));
    }
    float sloc[4] = {0.f, 0.f, 0.f, 0.f};
#pragma unroll
    for (int t = 0; t < 16; ++t)
#pragma unroll
        for (int r = 0; r < 4; ++r) {
            float e = __expf(acc[t][r] - mfin[r]);
            acc[t][r] = e;
            sloc[r] += e;
        }
#pragma unroll
    for (int off = 1; off < 16; off <<= 1)
#pragma unroll
        for (int r = 0; r < 4; ++r) sloc[r] += __shfl_xor(sloc[r], off, 64);
    __syncthreads();
    if (lm == 0)
#pragma unroll
        for (int r = 0; r < 4; ++r) red[quad * 4 + r][w] = sloc[r];
    __syncthreads();
    float inv[4];
#pragma unroll
    for (int r = 0; r < 4; ++r) {
        int row = quad * 4 + r;
        inv[r] = 1.f / (1.f + red[row][0] + red[row][1] + red[row][2] + red[row][3]);
    }
    // normalized weights -> LDS (bf16) only; global write comes later, coalesced
#pragma unroll
    for (int r = 0; r < 4; ++r) {
        int row = quad * 4 + r;
        float iv = inv[r];
#pragma unroll
        for (int t = 0; t < 16; ++t)
            Wl[row][kc0 + t * 16 + lm] = (bf16)(acc[t][r] * iv);
    }
    __syncthreads();

    // PV: O(16x64) = W(16x1024) @ V(1024x64), wave w covers k in [kc0,kc0+256)
    floatx4 opv[4];
#pragma unroll
    for (int ni = 0; ni < 4; ++ni) opv[ni] = (floatx4){0.f, 0.f, 0.f, 0.f};
#pragma unroll
    for (int i = 0; i < 8; ++i) {
        const int kk = kc0 + i * 32;
        bf16x8 a0 = *(const bf16x8*)&Wl[lm][kk + quad * 8];
#pragma unroll
        for (int ni = 0; ni < 4; ++ni) {
            bf16x8 bv = *(const bf16x8*)(Vt + ((long)(ni * 16 + lm) << 10) + kk + quad * 8);
            opv[ni] = MFMA16(a0, bv, opv[ni]);
        }
    }
    // coalesced attw write from Wl: 16 rows x 1024 cols fp32, float4/lane/iter
    {
        float* attp = attw + ((long)p << 20) + ((long)r0 << 10);
#pragma unroll
        for (int i = 0; i < 16; ++i) {
            int v4 = (i << 8) + tid;
            int row = v4 >> 8, col = (v4 & 255) << 2;
            bf16x4 wv = *(const bf16x4*)&Wl[row][col];
            floatx4 o = {(float)wv[0], (float)wv[1], (float)wv[2], (float)wv[3]};
            __builtin_nontemporal_store(o, (floatx4*)(attp + ((long)row << 10) + col));
        }
    }
    __syncthreads();
    float* Ored = (float*)&Wl[0][0];   // [4][16][64], aliases Wl (dead now)
#pragma unroll
    for (int ni = 0; ni < 4; ++ni)
#pragma unroll
        for (int r = 0; r < 4; ++r)
            Ored[(w * 16 + quad * 4 + r) * 64 + ni * 16 + lm] = opv[ni][r];
    __syncthreads();
    const float* x1p = x1 + ((long)b << 20) + ((long)r0 << 10) + (h << 6);
    float* xp = x + ((long)b << 20) + ((long)r0 << 10) + (h << 6);
#pragma unroll
    for (int j = 0; j < 4; ++j) {
        int el = tid + (j << 8);
        int row = el >> 6, cc = el & 63;
        float o = Ored[row * 64 + cc] + Ored[(16 + row) * 64 + cc]
                + Ored[(32 + row) * 64 + cc] + Ored[(48 + row) * 64 + cc];
        xp[((long)row << 10) + cc] = x1p[((long)row << 10) + cc] + o;
    }
}

// --------- FFN LN + transpose: xlT[b][l][c] = ffw[c]*(x-u)*rstd + ffb[c] ------
__global__ __launch_bounds__(256)
void ln_ffn_t_kernel(const float* __restrict__ x, const float* __restrict__ ps,
                     const float* __restrict__ pq, const float* __restrict__ fw,
                     const float* __restrict__ fb, bf16* __restrict__ xlT)
{
    __shared__ bf16 T[64][66];
    const int b = blockIdx.z;
    const int l0 = blockIdx.x << 6, c0 = blockIdx.y << 6;
    const int tid = threadIdx.x;
    const int ll = tid & 63, g = tid >> 6;
    float s = 0.f, q = 0.f;
#pragma unroll
    for (int c4 = 0; c4 < 4; ++c4) {
        s += ps[(b << 12) + (c4 << 10) + l0 + ll];
        q += pq[(b << 12) + (c4 << 10) + l0 + ll];
    }
    const float uu = s * (1.f / 1024.f);
    const float rr = rsqrtf(q * (1.f / 1024.f) - uu * uu + 1e-6f);
#pragma unroll
    for (int j = 0; j < 16; ++j) {
        int cc = (g << 4) + j;
        float v = x[((long)b << 20) + ((long)(c0 + cc) << 10) + l0 + ll];
        T[ll][cc] = (bf16)(fw[c0 + cc] * (v - uu) * rr + fb[c0 + cc]);
    }
    __syncthreads();
#pragma unroll
    for (int j = 0; j < 16; ++j) {
        int lr = (g << 4) + j;
        xlT[((long)b << 20) + ((long)(l0 + lr) << 10) + c0 + ll] = T[lr][ll];
    }
}

extern "C" void kernel_launch(void* const* d_in, const int* in_sizes, int n_in,
                              void* d_out, int out_size, void* d_ws, size_t ws_size,
                              hipStream_t stream)
{
    const float* x1      = (const float*)d_in[0];
    const float* lnq_w   = (const float*)d_in[1];
    const float* lnq_b   = (const float*)d_in[2];
    const float* lnk_w   = (const float*)d_in[3];
    const float* lnk_b   = (const float*)d_in[4];
    const float* lnv_w   = (const float*)d_in[5];
    const float* lnv_b   = (const float*)d_in[6];
    const float* wq      = (const float*)d_in[7];
    const float* bq      = (const float*)d_in[8];
    const float* wk      = (const float*)d_in[9];
    const float* bk      = (const float*)d_in[10];
    const float* wv      = (const float*)d_in[11];
    const float* bv      = (const float*)d_in[12];
    const float* ffnln_w = (const float*)d_in[13];
    const float* ffnln_b = (const float*)d_in[14];
    const float* conv1_w = (const float*)d_in[15];
    const float* conv1_b = (const float*)d_in[16];
    const float* conv2_w = (const float*)d_in[17];
    const float* conv2_b = (const float*)d_in[18];
    (void)in_sizes; (void)n_in; (void)out_size; (void)ws_size;

    char* ws = (char*)d_ws;
    // header: rsum_qkv (12KB) @0 + ps/pq partials (64KB each) -> 256KB
    const size_t OFF_VT   = 262144;                   //  8 MB VT        [h1T overlay]
    const size_t OFF_QKV  = OFF_VT   + 8388608;       // 24 MB q,k,v bf16 [h1T overlay]
    const size_t OFF_WQKV = OFF_QKV  + 25165824;      //  8 MB wq/wk/wv bf16 [xlT / part overlay]
    const size_t OFF_W1   = OFF_WQKV + 8388608;       //  8 MB conv1_w bf16  [part overlay]
    const size_t OFF_X    = OFF_W1   + 8388608;       // 16 MB x = x1 + attn_out (fp32)
    const size_t OFF_W2   = OFF_X    + 16777216;      //  8 MB conv2_w bf16
    float* rsum  = (float*)(ws + 0);
    float* ps    = (float*)(ws + 65536);
    float* pq    = (float*)(ws + 131072);
    bf16*  vt    = (bf16*)(ws + OFF_VT);
    bf16*  qkv   = (bf16*)(ws + OFF_QKV);
    bf16*  wqkvb = (bf16*)(ws + OFF_WQKV);
    bf16*  w1b   = (bf16*)(ws + OFF_W1);
    float* x     = (float*)(ws + OFF_X);
    bf16*  w2b   = (bf16*)(ws + OFF_W2);
    bf16*  h1T   = (bf16*)(ws + OFF_VT);              // 32 MB, overlays vt+qkv (dead post-attn)
    bf16*  xlT   = (bf16*)(ws + OFF_WQKV);            //  8 MB, overlays wqkvb (dead post-QKV)
    float* part  = (float*)(ws + OFF_WQKV);           // 16 MB, overlays wqkvb+w1b (dead at conv2)

    float* out0 = (float*)d_out;
    float* attw = (float*)((char*)d_out + 16777216);  // 4*16*1024*1024 fp32
    bf16*  xn   = (bf16*)attw;                        //  8 MB scratch, dead before attn writes

    // 1. weight casts + QKV row-sums + LN stats of x1 (fused)
    cast_all<<<11568, 256, 0, stream>>>(wq, wqkvb, wk, wqkvb + (1 << 20),
                                        wv, wqkvb + (2 << 20), conv1_w, w1b, conv2_w, w2b,
                                        rsum, x1, ps, pq);
    // 2. single normalized input xn (bf16)
    ln_x1_kernel<<<4096, 256, 0, stream>>>(x1, ps, pq, xn);
    // 3. QKV projections: shared A (sAz=0), LN affine folded into epilogue
    gemm_nt<0><<<dim3(8, 32, 3), 256, 0, stream>>>(xn, wqkvb, qkv, nullptr,
                                                   bq, bk, bv, nullptr,
                                                   lnq_w, lnk_w, lnv_w,
                                                   lnq_b, lnk_b, lnv_b, rsum,
                                                   0, 1L << 20, 1L << 22, 0, 0,
                                                   4096, 1024, 1024, 1024, 1);
    // 4. V^T slabs for PV B-operand
    vtrans_kernel<<<dim3(16, 64), 256, 0, stream>>>(qkv + (2L << 22), vt);
    // 5. fused attention (attn weights fp32 + x = x1 + o), XCD-aware 1D grid
    attn_kernel<<<4096, 256, 0, stream>>>(qkv, qkv + (1L << 22), vt, x1, attw, x);
    // 6. FFN LN stats of x (partials only)
    stats_part<<<dim3(16, 4, 4), 256, 0, stream>>>(x, ps, pq);
    // 7. FFN LN + transpose -> xlT (bf16)
    ln_ffn_t_kernel<<<dim3(16, 16, 4), 256, 0, stream>>>(x, ps, pq, ffnln_w, ffnln_b, xlT);
    // 8. conv1: h1T[b] = gelu(xlT[b] @ conv1_w^T + b1)   (M=1024,N=4096,K=1024)
    gemm_nt<1><<<dim3(32, 8, 4), 256, 0, stream>>>(xlT, w1b, h1T, nullptr,
                                                   conv1_b, conv1_b, conv1_b, nullptr,
                                                   nullptr, nullptr, nullptr,
                                                   nullptr, nullptr, nullptr, nullptr,
                                                   1L << 20, 0, 1L << 22, 0, 0,
                                                   1024, 4096, 1024, 1024, 1);
    // 9. conv2 split-K: out0[b] = conv2_w @ h1T[b]^T + b2 + x[b]  (K=4096 -> 2x2048)
    gemm_nt<2><<<dim3(8, 8, 8), 256, 0, stream>>>(w2b, h1T, out0, part,
                                                  conv2_b, conv2_b, conv2_b, x,
                                                  nullptr, nullptr, nullptr,
                                                  nullptr, nullptr, nullptr, nullptr,
                                                  0, 1L << 22, 1L << 20, 1L << 20,
                                                  1L << 20, 1024, 1024, 4096, 2048, 2);
    // 10. out0 += part
    addpart<<<4096, 256, 0, stream>>>(out0, part);
}